// Round 3
// baseline (141.551 us; speedup 1.0000x reference)
//
#include <hip/hip_runtime.h>

// RoutingMaskLayer: out[b,h,w,j] = in[b,h,w, argmax(routing[b,:])*RW + j]
// in [32,56,56,256] f32, routing [32,4] f32, out [32,56,56,64] f32.
// Pure memory-bound gather: selected channels are a contiguous 256 B block
// per pixel. R3 = R2 with native clang vector type so
// __builtin_nontemporal_store accepts it (HIP_vector_type struct is not a
// valid nontemporal operand).

#define NB 32
#define NH 56
#define NW 56
#define NC 256
#define NROUTES 4
#define RW (NC / NROUTES)                  // 64 selected channels / sample
#define PIX_F4 (RW / 4)                    // 16 vec4 per output pixel
#define TOTAL_F4 (NB * NH * NW * PIX_F4)   // 1,605,632
#define ITEMS 4                            // vec4s per thread
#define BLOCK 256
#define GRID (TOTAL_F4 / (BLOCK * ITEMS))  // 1568, exact — no tail

typedef float f32x4 __attribute__((ext_vector_type(4)));  // native vector, 16 B

__global__ __launch_bounds__(BLOCK) void
RoutingMaskLayer_51453708206705_kernel(const f32x4* __restrict__ in,
                                       const float* __restrict__ routing,
                                       f32x4* __restrict__ out) {
    const int base = blockIdx.x * (BLOCK * ITEMS) + threadIdx.x;

    int bPrev = -1, route = 0;
#pragma unroll
    for (int k = 0; k < ITEMS; ++k) {
        const int i   = base + k * BLOCK;      // output vec4 index
        const int pix = i >> 4;                // (b,h,w) pixel
        const int j4  = i & 15;                // vec4 within selected block
        const int b   = pix / (NH * NW);       // sample (magic-mul)

        if (b != bPrev) {                      // at most one switch per thread
            bPrev = b;
            const float* r = routing + b * NROUTES;
            float r0 = r[0], r1 = r[1], r2 = r[2], r3 = r[3];
            route = 0; float best = r0;
            if (r1 > best) { best = r1; route = 1; }
            if (r2 > best) { best = r2; route = 2; }
            if (r3 > best) { best = r3; route = 3; }
        }

        const f32x4 v = in[pix * (NC / 4) + route * PIX_F4 + j4];
        __builtin_nontemporal_store(v, &out[i]);   // out is never re-read here
    }
}

extern "C" void kernel_launch(void* const* d_in, const int* in_sizes, int n_in,
                              void* d_out, int out_size, void* d_ws, size_t ws_size,
                              hipStream_t stream) {
    const f32x4* in      = (const f32x4*)d_in[0];
    const float* routing = (const float*)d_in[1];
    f32x4*       out     = (f32x4*)d_out;

    RoutingMaskLayer_51453708206705_kernel<<<GRID, BLOCK, 0, stream>>>(in, routing, out);
}